// Round 7
// baseline (10887.066 us; speedup 1.0000x reference)
//
#include <hip/hip_runtime.h>

#define N_NODES 200000
#define DIM 64
#define BSHIFT 8                       // 256 rows per dest bucket
#define BROWS 256
#define NB 782                         // ceil(200000 / 256)
#define NB_PAD 1024
#define CHUNK 4096                     // edges per bucket_scatter block
#define NS 8                           // source stripes (25000 nodes, 3.2 MB bf16 each)
#define APITCH 65                      // fp32 acc row pitch (bank spread; 65%32=1)

__device__ __forceinline__ float bf2f(unsigned short u) {
    return __uint_as_float(((unsigned int)u) << 16);
}
__device__ __forceinline__ unsigned short f2bf(float f) {
    unsigned int u = __float_as_uint(f);
    u += 0x7FFFu + ((u >> 16) & 1u);   // round-to-nearest-even
    return (unsigned short)(u >> 16);
}
__device__ __forceinline__ int stripe_of(int c) { return (int)((unsigned)c / 25000u); }

// ---- Pass A: dest-bucket histogram (LDS-staged) ----
__global__ __launch_bounds__(256) void bucket_hist(const int* __restrict__ rows, int E,
                                                   int* __restrict__ bcnt) {
    __shared__ int h[NB_PAD];
    for (int i = threadIdx.x; i < NB_PAD; i += 256) h[i] = 0;
    __syncthreads();
    int stride = gridDim.x * blockDim.x;
    for (int e = blockIdx.x * blockDim.x + threadIdx.x; e < E; e += stride)
        atomicAdd(&h[rows[e] >> BSHIFT], 1);
    __syncthreads();
    for (int i = threadIdx.x; i < NB; i += 256)
        if (h[i]) atomicAdd(&bcnt[i], h[i]);
}

// ---- Pass B: wave-parallel exclusive scan of 782 bucket counts ----
__global__ __launch_bounds__(1024) void bucket_scan(const int* __restrict__ bcnt,
                                                    int* __restrict__ bbase,
                                                    int* __restrict__ bcur) {
    __shared__ int wsum[16];
    int t = threadIdx.x;
    int v = (t < NB) ? bcnt[t] : 0;
    int incl = v;
    for (int off = 1; off < 64; off <<= 1) {
        int u = __shfl_up(incl, off);
        if ((t & 63) >= off) incl += u;
    }
    if ((t & 63) == 63) wsum[t >> 6] = incl;
    __syncthreads();
    if (t < 16) {
        int w = wsum[t];
        for (int off = 1; off < 16; off <<= 1) {
            int u = __shfl_up(w, off);
            if (t >= off) w += u;
        }
        wsum[t] = w;                    // inclusive wave sums
    }
    __syncthreads();
    int wb = (t >= 64) ? wsum[(t >> 6) - 1] : 0;
    int excl = wb + incl - v;
    if (t < NB) { bbase[t] = excl; bcur[t] = excl; }
    if (t == NB - 1) bbase[NB] = excl + v;
}

// ---- Pass C: chunked scatter into dest-bucket-grouped tmp (round-1 proven form) ----
__global__ __launch_bounds__(512) void bucket_scatter(const int* __restrict__ rows,
                                                      const int* __restrict__ cols,
                                                      const float* __restrict__ vals, int E,
                                                      int* __restrict__ bcur,
                                                      int2* __restrict__ tmp) {
    __shared__ int h[NB_PAD];          // counts, later reused as fix (g - excl)
    __shared__ int cur2[NB_PAD];       // block-local exclusive, then atomic cursor
    __shared__ int wtot[8];
    __shared__ int2 stage[CHUNK];
    __shared__ unsigned short sbkt[CHUNK];
    const int base = blockIdx.x * CHUNK;
    const int count = min(CHUNK, E - base);
    const int t = threadIdx.x;

    for (int i = t; i < NB_PAD; i += 512) h[i] = 0;
    __syncthreads();

    int myr[8], myc[8];
    float myv[8];
#pragma unroll
    for (int k = 0; k < 8; ++k) {
        int i = t + k * 512;
        if (i < count) {
            myr[k] = rows[base + i];
            myc[k] = cols[base + i];
            myv[k] = vals[base + i];
            atomicAdd(&h[myr[k] >> BSHIFT], 1);
        }
    }
    __syncthreads();

    // scan 1024 bins: 2 bins per thread, wave scan + cross-wave totals
    int h0 = h[2 * t], h1 = h[2 * t + 1];
    int s = h0 + h1;
    int incl = s;
    for (int off = 1; off < 64; off <<= 1) {
        int u = __shfl_up(incl, off);
        if ((t & 63) >= off) incl += u;
    }
    if ((t & 63) == 63) wtot[t >> 6] = incl;
    __syncthreads();
    int wb = 0;
    for (int w = 0; w < (t >> 6); ++w) wb += wtot[w];
    int excl = wb + incl - s;
    cur2[2 * t] = excl;
    cur2[2 * t + 1] = excl + h0;
    __syncthreads();

    // reserve global ranges; h becomes fix = g - excl
    for (int i = t; i < NB; i += 512) {
        int hi = h[i];
        int g = hi ? atomicAdd(&bcur[i], hi) : 0;
        h[i] = g - cur2[i];
    }
    __syncthreads();

    // stage in bucket-grouped order
#pragma unroll
    for (int k = 0; k < 8; ++k) {
        int i = t + k * 512;
        if (i < count) {
            int r = myr[k];
            int b = r >> BSHIFT;
            int slot = atomicAdd(&cur2[b], 1);
            stage[slot] = make_int2(((r & (BROWS - 1)) << 18) | myc[k], __float_as_int(myv[k]));
            sbkt[slot] = (unsigned short)b;
        }
    }
    __syncthreads();
    for (int s2 = t; s2 < count; s2 += 512)
        tmp[s2 + h[sbkt[s2]]] = stage[s2];
}

// ---- Pass D: per-bucket STRIPE grouping (8 bins) + rs3 emission ----
// No per-row sort needed: spmm is edge-parallel and keys carry row_local.
__global__ __launch_bounds__(512) void bucket_sort(const int2* __restrict__ tmp,
                                                   const int* __restrict__ bbase,
                                                   int2* __restrict__ sorted,
                                                   int* __restrict__ rs3) {
    __shared__ int h[NS];
    __shared__ int hb[NS + 1];
    const int bk = blockIdx.x;
    const int s0 = bbase[bk], s1 = bbase[bk + 1];
    const int t = threadIdx.x;
    if (t < NS) h[t] = 0;
    __syncthreads();
    for (int e = s0 + t; e < s1; e += 512)
        atomicAdd(&h[stripe_of(tmp[e].x & 0x3FFFF)], 1);
    __syncthreads();
    if (t == 0) {
        int run = s0;
#pragma unroll
        for (int i = 0; i < NS; ++i) { hb[i] = run; run += h[i]; }
        hb[NS] = s1;
    }
    __syncthreads();
    if (t < NS) h[t] = hb[t];          // global cursors
    if (t < NS + 1) rs3[bk * (NS + 1) + t] = hb[t];
    __syncthreads();
    for (int e = s0 + t; e < s1; e += 512) {
        int2 kv = tmp[e];
        int rank = atomicAdd(&h[stripe_of(kv.x & 0x3FFFF)], 1);
        sorted[rank] = kv;
    }
}

// ---- fp32 -> bf16 convert (embeds -> xb0) ----
__global__ __launch_bounds__(256) void convert_kernel(const float* __restrict__ src,
                                                      unsigned short* __restrict__ dst, int n4) {
    int i = blockIdx.x * blockDim.x + threadIdx.x;
    if (i >= n4) return;
    float4 v = *(const float4*)(src + i * 4);
    ushort4 o;
    o.x = f2bf(v.x); o.y = f2bf(v.y); o.z = f2bf(v.z); o.w = f2bf(v.w);
    *(ushort4*)(dst + i * 4) = o;
}

#define BF_LO(u) __uint_as_float((u) << 16)
#define BF_HI(u) __uint_as_float((u) & 0xFFFF0000u)

// ---- SpMM: stripe-phased, EDGE-PARALLEL, LDS fp32 accumulator ----
// One block per 256-row bucket; 2 blocks/CU (66.6 KB LDS). Per stripe phase the
// block streams its contiguous ~1024-edge slab edge-parallel: 64 groups x 8
// feat-lanes, group g takes edges a+g, a+g+64, ... (uniform, no predication,
// 2 gathers in flight + prefetched edge loads). Contributions accumulate via
// ds_add_f32 into acc[256][65] (pitch 65 spreads banks; ~2 lanes/bank = free).
// All co-resident blocks sweep stripes near-lockstep (work/phase +-3%), so the
// gather working set per phase is one 3.2 MB stripe (< 4 MB L2/XCD).
__global__ __launch_bounds__(512, 2) void spmm_kernel(const int2* __restrict__ sorted,
                                                      const int* __restrict__ rs3,
                                                      const unsigned short* __restrict__ xb,
                                                      unsigned short* __restrict__ y) {
    __shared__ float acc[BROWS * APITCH];
    __shared__ int rsl[NS + 1];
    const int bk = blockIdx.x;
    const int t = threadIdx.x;
    if (t < NS + 1) rsl[t] = rs3[bk * (NS + 1) + t];
    for (int i = t; i < BROWS * APITCH; i += 512) acc[i] = 0.f;
    __syncthreads();
    const int grp = t >> 3;            // 64 edge groups
    const int f3 = (t & 7) << 3;       // feat offset: 8 lanes x 8 feats
    const long long* sll = (const long long*)sorted;

#pragma unroll 1
    for (int s = 0; s < NS; ++s) {
        const int b = rsl[s + 1];
        int e = rsl[s] + grp;
        long long qA = 0, qB = 0;
        if (e < b)      qA = __builtin_nontemporal_load(sll + e);
        if (e + 64 < b) qB = __builtin_nontemporal_load(sll + e + 64);
        while (e < b) {
            long long qA2 = 0, qB2 = 0;
            if (e + 128 < b) qA2 = __builtin_nontemporal_load(sll + e + 128);
            if (e + 192 < b) qB2 = __builtin_nontemporal_load(sll + e + 192);

            int keyA = (int)(unsigned int)qA;
            float vA = __int_as_float((int)((unsigned long long)qA >> 32));
            int cA = keyA & 0x3FFFF;
            int rlA = (int)((unsigned)keyA >> 18);
            uint4 gA = *(const uint4*)(xb + (cA << 6) + f3);

            const bool hasB = (e + 64 < b);
            int keyB = (int)(unsigned int)qB;
            float vB = __int_as_float((int)((unsigned long long)qB >> 32));
            int cB = keyB & 0x3FFFF;
            int rlB = (int)((unsigned)keyB >> 18);
            uint4 gB = make_uint4(0u, 0u, 0u, 0u);
            if (hasB) gB = *(const uint4*)(xb + (cB << 6) + f3);

            float* apA = acc + rlA * APITCH + f3;
            atomicAdd(apA + 0, vA * BF_LO(gA.x));
            atomicAdd(apA + 1, vA * BF_HI(gA.x));
            atomicAdd(apA + 2, vA * BF_LO(gA.y));
            atomicAdd(apA + 3, vA * BF_HI(gA.y));
            atomicAdd(apA + 4, vA * BF_LO(gA.z));
            atomicAdd(apA + 5, vA * BF_HI(gA.z));
            atomicAdd(apA + 6, vA * BF_LO(gA.w));
            atomicAdd(apA + 7, vA * BF_HI(gA.w));
            if (hasB) {
                float* apB = acc + rlB * APITCH + f3;
                atomicAdd(apB + 0, vB * BF_LO(gB.x));
                atomicAdd(apB + 1, vB * BF_HI(gB.x));
                atomicAdd(apB + 2, vB * BF_LO(gB.y));
                atomicAdd(apB + 3, vB * BF_HI(gB.y));
                atomicAdd(apB + 4, vB * BF_LO(gB.z));
                atomicAdd(apB + 5, vB * BF_HI(gB.z));
                atomicAdd(apB + 6, vB * BF_LO(gB.w));
                atomicAdd(apB + 7, vB * BF_HI(gB.w));
            }
            qA = qA2; qB = qB2; e += 128;
        }
        __syncthreads();               // phase alignment (correctness holds without)
    }

    // epilogue: acc -> bf16 y (wave writes 8 rows x 128 B, coalesced)
#pragma unroll
    for (int rr = t >> 3; rr < BROWS; rr += 64) {
        int r = (bk << BSHIFT) + rr;
        if (r < N_NODES) {
            const float* ap = acc + rr * APITCH + f3;
            uint4 yo;
            yo.x = (unsigned)f2bf(ap[0]) | ((unsigned)f2bf(ap[1]) << 16);
            yo.y = (unsigned)f2bf(ap[2]) | ((unsigned)f2bf(ap[3]) << 16);
            yo.z = (unsigned)f2bf(ap[4]) | ((unsigned)f2bf(ap[5]) << 16);
            yo.w = (unsigned)f2bf(ap[6]) | ((unsigned)f2bf(ap[7]) << 16);
            *(uint4*)(y + (r << 6) + f3) = yo;
        }
    }
}

// ---- final merge: acc = 0.2 * (embeds + y1 + y2 + y3 + y4), pure streaming ----
__global__ __launch_bounds__(256) void merge_kernel(const float* __restrict__ emb,
                                                    const unsigned short* __restrict__ y1,
                                                    const unsigned short* __restrict__ y2,
                                                    const unsigned short* __restrict__ y3,
                                                    const unsigned short* __restrict__ y4,
                                                    float* __restrict__ acc, int n8) {
    int i = blockIdx.x * blockDim.x + threadIdx.x;
    if (i >= n8) return;
    int o = i * 8;
    uint4 a = *(const uint4*)(y1 + o);
    uint4 b = *(const uint4*)(y2 + o);
    uint4 c = *(const uint4*)(y3 + o);
    uint4 d = *(const uint4*)(y4 + o);
    float4 x0 = *(const float4*)(emb + o);
    float4 x1 = *(const float4*)(emb + o + 4);
    const float sc = 0.2f;
    float4 o0, o1;
    o0.x = (x0.x + BF_LO(a.x) + BF_LO(b.x) + BF_LO(c.x) + BF_LO(d.x)) * sc;
    o0.y = (x0.y + BF_HI(a.x) + BF_HI(b.x) + BF_HI(c.x) + BF_HI(d.x)) * sc;
    o0.z = (x0.z + BF_LO(a.y) + BF_LO(b.y) + BF_LO(c.y) + BF_LO(d.y)) * sc;
    o0.w = (x0.w + BF_HI(a.y) + BF_HI(b.y) + BF_HI(c.y) + BF_HI(d.y)) * sc;
    o1.x = (x1.x + BF_LO(a.z) + BF_LO(b.z) + BF_LO(c.z) + BF_LO(d.z)) * sc;
    o1.y = (x1.y + BF_HI(a.z) + BF_HI(b.z) + BF_HI(c.z) + BF_HI(d.z)) * sc;
    o1.z = (x1.z + BF_LO(a.w) + BF_LO(b.w) + BF_LO(c.w) + BF_LO(d.w)) * sc;
    o1.w = (x1.w + BF_HI(a.w) + BF_HI(b.w) + BF_HI(c.w) + BF_HI(d.w)) * sc;
    *(float4*)(acc + o) = o0;
    *(float4*)(acc + o + 4) = o1;
}

extern "C" void kernel_launch(void* const* d_in, const int* in_sizes, int n_in,
                              void* d_out, int out_size, void* d_ws, size_t ws_size,
                              hipStream_t stream) {
    const float* embeds = (const float*)d_in[0];
    const int*   rows   = (const int*)d_in[1];
    const int*   cols   = (const int*)d_in[2];
    const float* vals   = (const float*)d_in[3];
    float* acc = (float*)d_out;
    const int E = in_sizes[1];

    char* ws = (char*)d_ws;
    size_t off = 0;
    auto alloc = [&](size_t bytes) -> char* {
        char* p = ws + off;
        off = (off + bytes + 255) & ~(size_t)255;
        return p;
    };
    int*   bcnt   = (int*)alloc((size_t)NB * 4);
    int*   bbase  = (int*)alloc((size_t)(NB + 1) * 4);
    int*   bcur   = (int*)alloc((size_t)NB * 4);
    int*   rs3    = (int*)alloc((size_t)NB * (NS + 1) * 4);                  // 28 KB
    int2*  sorted = (int2*)alloc((size_t)E * 8);                             // 51.2 MB
    unsigned short* xb0 = (unsigned short*)alloc((size_t)N_NODES * DIM * 2); // 25.6 MB
    unsigned short* xb1 = (unsigned short*)alloc((size_t)N_NODES * DIM * 2); // 25.6 MB
    unsigned short* xb2 = (unsigned short*)alloc((size_t)N_NODES * DIM * 2); // 25.6 MB
    int2*  tmp    = (int2*)alloc((size_t)E * 8);                             // 51.2 MB
    // xb3/xb4 alias tmp (dead after bucket_sort); tmp = 51.2 MB = exactly 2x25.6
    unsigned short* xb3 = (unsigned short*)tmp;
    unsigned short* xb4 = xb3 + (size_t)N_NODES * DIM;

    hipMemsetAsync(bcnt, 0, (size_t)NB * 4, stream);

    bucket_hist<<<1024, 256, 0, stream>>>(rows, E, bcnt);
    bucket_scan<<<1, 1024, 0, stream>>>(bcnt, bbase, bcur);
    bucket_scatter<<<(E + CHUNK - 1) / CHUNK, 512, 0, stream>>>(rows, cols, vals, E, bcur, tmp);
    bucket_sort<<<NB, 512, 0, stream>>>(tmp, bbase, sorted, rs3);

    int n4 = N_NODES * DIM / 4;
    convert_kernel<<<(n4 + 255) / 256, 256, 0, stream>>>(embeds, xb0, n4);

    spmm_kernel<<<NB, 512, 0, stream>>>(sorted, rs3, xb0, xb1);
    spmm_kernel<<<NB, 512, 0, stream>>>(sorted, rs3, xb1, xb2);
    spmm_kernel<<<NB, 512, 0, stream>>>(sorted, rs3, xb2, xb3);
    spmm_kernel<<<NB, 512, 0, stream>>>(sorted, rs3, xb3, xb4);

    int n8 = N_NODES * DIM / 8;
    merge_kernel<<<(n8 + 255) / 256, 256, 0, stream>>>(embeds, xb1, xb2, xb3, xb4, acc, n8);
}